// Round 18
// baseline (37.792 us; speedup 1.0000x reference)
//
#include <hip/hip_runtime.h>

#define Hd    256
#define OUTD  10
#define DDEP  10
#define KSTR  12
#define TLEN  8192
#define NTHR  1024
#define NBLK  256
#define TILE  2048

typedef __attribute__((ext_vector_type(8))) short bf16x8;
typedef __attribute__((ext_vector_type(4))) float f32x4;

__device__ __forceinline__ int ph(int j) { return j + (j >> 5); }

// bf16 round-to-nearest-even helpers (no NaN in this data)
__device__ __forceinline__ unsigned bfr(float x) {
    unsigned u = __float_as_uint(x);
    return (u + 0x7FFFu + ((u >> 16) & 1u)) >> 16;
}
__device__ __forceinline__ unsigned bfpk(float lo, float hi) {
    unsigned uh = __float_as_uint(hi);
    unsigned h  = (uh + 0x7FFFu + ((uh >> 16) & 1u)) & 0xFFFF0000u;
    return bfr(lo) | h;
}

// LDS float/u32 offsets (r13/r14/r16-proven map):
//  [0, 32768)      W2h: W2 bf16 [256 rows][128 u32, XOR-swizzled]; dead after A-frag build
//  [32768, 35328)  Vs fp32 [10][256] chain history
//  [35328, 37888)  W3s [10][256]
//  [37888, 38144)  Vbf [2][128] u32 bf16-pair ping-pong
//  [38144, 38272)  Ks [10][12] (+pad)
//  [38272, ...)    xs conv window (swizzled)
#define OFF_W2H 0
#define OFF_VS  32768
#define OFF_W3  35328
#define OFF_VBF 37888
#define OFF_KS  38144
#define OFF_XS  38272
#define XS_LOG  (TILE + DDEP)
#define SMEM_FLOATS (OFF_XS + XS_LOG + (XS_LOG >> 5) + 4)   // 161592 B < 160 KiB

__global__ __launch_bounds__(NTHR, 1) void fused_rnn_kernel(
    const float* __restrict__ x, const float* __restrict__ w1g,
    const float* __restrict__ W2, const float* __restrict__ W3,
    float* __restrict__ y)
{
    __shared__ float smem[SMEM_FLOATS];
    unsigned* W2u = (unsigned*)(smem + OFF_W2H);
    float* Vs  = smem + OFF_VS;
    float* W3s = smem + OFF_W3;
    unsigned* Vbf = (unsigned*)(smem + OFF_VBF);
    float* Ks  = smem + OFF_KS;
    float* xs  = smem + OFF_XS;

    const int tid = threadIdx.x;
    const int bid = blockIdx.x;
    const int b   = bid >> 2;
    const int t0  = (bid & 3) * TILE;
    const float* xb = x + b * TLEN;

    // ---- stage W2 -> bf16 LDS (coalesced float4 reads; 16 iters/thread) ----
    const float4* W2v4 = (const float4*)W2;
    for (int g = tid; g < 16384; g += NTHR) {
        const float4 f = W2v4[g];
        const int row  = g >> 6;
        const int c    = (g & 63) * 2;               // u32 col (even)
        const int phys = c ^ ((row & 7) << 2);       // XOR-swizzle bits 2..4
        *(uint2*)&W2u[row * 128 + phys] =
            make_uint2(bfpk(f.x, f.y), bfpk(f.z, f.w));
    }

    // ---- stage xs (swizzled), W3s, v0 (fp32 + bf16) ----
    for (int j = tid; j < XS_LOG; j += NTHR) {
        const int g = t0 - DDEP + j;
        xs[ph(j)] = (g >= 0) ? xb[g] : 0.0f;
    }
    for (int i = tid; i < OUTD * Hd; i += NTHR) W3s[i] = W3[i];
    if (tid < Hd) Vs[tid] = w1g[tid];
    if (tid < 128) Vbf[tid] = bfpk(w1g[2 * tid], w1g[2 * tid + 1]);
    __syncthreads();

    // ---- build A-frags from LDS: chain waves 0-7, wave w owns rows [32w, 32w+32) ----
    const int w = tid >> 6, l = tid & 63;
    bf16x8 Afr[2][8];
    if (w < 8) {
        #pragma unroll
        for (int rt = 0; rt < 2; ++rt) {
            const int row = 32 * w + 16 * rt + (l & 15);
            #pragma unroll
            for (int kt = 0; kt < 8; ++kt) {
                const int c    = kt * 16 + (l >> 4) * 4;   // u32 col, 4-aligned
                const int phys = c ^ ((row & 7) << 2);
                Afr[rt][kt] = __builtin_bit_cast(bf16x8,
                    *(const int4*)&W2u[row * 128 + phys]);
            }
        }
    }
    __syncthreads();       // W2h dead from here

    // ---- chain: v_{d+1} = W2 * v_d, 9 serial MFMA iterations (8 waves, r13 layout) ----
    #pragma unroll 1
    for (int d = 0; d < DDEP - 1; ++d) {
        if (w < 8) {
            const unsigned* vbf = Vbf + (d & 1) * 128;
            f32x4 acc0 = {0.f, 0.f, 0.f, 0.f};
            f32x4 acc1 = {0.f, 0.f, 0.f, 0.f};
            #pragma unroll
            for (int kt = 0; kt < 8; ++kt) {
                const bf16x8 Bfr = __builtin_bit_cast(bf16x8,
                    *(const int4*)&vbf[kt * 16 + (l >> 4) * 4]);
                acc0 = __builtin_amdgcn_mfma_f32_16x16x32_bf16(Afr[0][kt], Bfr, acc0, 0, 0, 0);
                acc1 = __builtin_amdgcn_mfma_f32_16x16x32_bf16(Afr[1][kt], Bfr, acc1, 0, 0, 0);
            }
            // C layout: col = lane&15, row = (lane>>4)*4 + reg (m89-verified)
            if ((l & 15) == 0) {
                const int g  = l >> 4;
                const int r0 = 32 * w + 4 * g;
                const int r1 = r0 + 16;
                *(f32x4*)&Vs[(d + 1) * Hd + r0] = acc0;
                *(f32x4*)&Vs[(d + 1) * Hd + r1] = acc1;
                unsigned* dst = Vbf + ((d + 1) & 1) * 128;
                *(uint2*)&dst[r0 >> 1] =
                    make_uint2(bfpk(acc0.x, acc0.y), bfpk(acc0.z, acc0.w));
                *(uint2*)&dst[r1 >> 1] =
                    make_uint2(bfpk(acc1.x, acc1.y), bfpk(acc1.z, acc1.w));
            }
        }
        __syncthreads();
    }

    // ---- K[d][o] = W3[o] . v_d : wave w handles d = w (w < 10) ----
    if (w < DDEP) {
        const int d = w;
        const float4 vv = ((const float4*)(Vs + d * Hd))[l];
        #pragma unroll
        for (int o = 0; o < OUTD; ++o) {
            const float4 wv = ((const float4*)(W3s + o * Hd))[l];
            float p = fmaf(wv.x, vv.x,
                      fmaf(wv.y, vv.y,
                      fmaf(wv.z, vv.z, wv.w * vv.w)));
            p += __shfl_xor(p, 1);  p += __shfl_xor(p, 2);
            p += __shfl_xor(p, 4);  p += __shfl_xor(p, 8);
            p += __shfl_xor(p, 16); p += __shfl_xor(p, 32);
            if (l == 0) Ks[d * KSTR + o] = p;
        }
        if (l == 1) { Ks[d * KSTR + 10] = 0.f; Ks[d * KSTR + 11] = 0.f; }
    }
    __syncthreads();

    // ---- causal FIR: 2 consecutive positions per thread ----
    const int ub = tid * 2;
    float acc0[OUTD], acc1[OUTD];
    #pragma unroll
    for (int o = 0; o < OUTD; ++o) { acc0[o] = 0.f; acc1[o] = 0.f; }

    float wn0 = xs[ph(ub + DDEP)];
    float wn1 = xs[ph(ub + DDEP + 1)];

    #pragma unroll
    for (int d = 0; d < DDEP; ++d) {
        const float4 kA = *(const float4*)&Ks[d * KSTR];
        const float4 kB = *(const float4*)&Ks[d * KSTR + 4];
        const float2 kC = *(const float2*)&Ks[d * KSTR + 8];
        acc0[0] = fmaf(kA.x, wn0, acc0[0]);  acc1[0] = fmaf(kA.x, wn1, acc1[0]);
        acc0[1] = fmaf(kA.y, wn0, acc0[1]);  acc1[1] = fmaf(kA.y, wn1, acc1[1]);
        acc0[2] = fmaf(kA.z, wn0, acc0[2]);  acc1[2] = fmaf(kA.z, wn1, acc1[2]);
        acc0[3] = fmaf(kA.w, wn0, acc0[3]);  acc1[3] = fmaf(kA.w, wn1, acc1[3]);
        acc0[4] = fmaf(kB.x, wn0, acc0[4]);  acc1[4] = fmaf(kB.x, wn1, acc1[4]);
        acc0[5] = fmaf(kB.y, wn0, acc0[5]);  acc1[5] = fmaf(kB.y, wn1, acc1[5]);
        acc0[6] = fmaf(kB.z, wn0, acc0[6]);  acc1[6] = fmaf(kB.z, wn1, acc1[6]);
        acc0[7] = fmaf(kB.w, wn0, acc0[7]);  acc1[7] = fmaf(kB.w, wn1, acc1[7]);
        acc0[8] = fmaf(kC.x, wn0, acc0[8]);  acc1[8] = fmaf(kC.x, wn1, acc1[8]);
        acc0[9] = fmaf(kC.y, wn0, acc0[9]);  acc1[9] = fmaf(kC.y, wn1, acc1[9]);
        wn1 = wn0;
        wn0 = xs[ph(ub + DDEP - 1 - d)];
    }

    // ---- direct coalesced y stores: 20 consecutive floats per thread ----
    // (positions 2*tid, 2*tid+1 -> y offset 20*tid, 80 B aligned, wave-contiguous)
    float* yg = y + ((size_t)b * TLEN + t0) * OUTD + ub * OUTD;
    f32x4 v0, v1, v2, v3, v4;
    v0.x = acc0[0]; v0.y = acc0[1]; v0.z = acc0[2]; v0.w = acc0[3];
    v1.x = acc0[4]; v1.y = acc0[5]; v1.z = acc0[6]; v1.w = acc0[7];
    v2.x = acc0[8]; v2.y = acc0[9]; v2.z = acc1[0]; v2.w = acc1[1];
    v3.x = acc1[2]; v3.y = acc1[3]; v3.z = acc1[4]; v3.w = acc1[5];
    v4.x = acc1[6]; v4.y = acc1[7]; v4.z = acc1[8]; v4.w = acc1[9];
    __builtin_nontemporal_store(v0, (f32x4*)(yg));
    __builtin_nontemporal_store(v1, (f32x4*)(yg + 4));
    __builtin_nontemporal_store(v2, (f32x4*)(yg + 8));
    __builtin_nontemporal_store(v3, (f32x4*)(yg + 12));
    __builtin_nontemporal_store(v4, (f32x4*)(yg + 16));
}

extern "C" void kernel_launch(void* const* d_in, const int* in_sizes, int n_in,
                              void* d_out, int out_size, void* d_ws, size_t ws_size,
                              hipStream_t stream)
{
    const float* x  = (const float*)d_in[0];   // (64, 8192)
    const float* w1 = (const float*)d_in[1];   // (256, 1) contiguous
    const float* W2 = (const float*)d_in[2];   // (256, 256)
    const float* W3 = (const float*)d_in[3];   // (10, 256)
    float* y  = (float*)d_out;

    fused_rnn_kernel<<<NBLK, dim3(NTHR), 0, stream>>>(x, w1, W2, W3, y);
}

// Round 19
// 22.548 us; speedup vs baseline: 1.6760x; 1.6760x over previous
//
#include <hip/hip_runtime.h>

#define Hd    256
#define OUTD  10
#define DDEP  10
#define KSTR  12
#define TLEN  8192
#define NTHR  1024
#define NBLK  256
#define TILE  2048

typedef __attribute__((ext_vector_type(8))) short bf16x8;
typedef __attribute__((ext_vector_type(4))) float f32x4;

__device__ __forceinline__ int ph(int j) { return j + (j >> 5); }

// bf16 round-to-nearest-even helpers (no NaN in this data)
__device__ __forceinline__ unsigned bfr(float x) {
    unsigned u = __float_as_uint(x);
    return (u + 0x7FFFu + ((u >> 16) & 1u)) >> 16;
}
__device__ __forceinline__ unsigned bfpk(float lo, float hi) {
    unsigned uh = __float_as_uint(hi);
    unsigned h  = (uh + 0x7FFFu + ((uh >> 16) & 1u)) & 0xFFFF0000u;
    return bfr(lo) | h;
}

// LDS float/u32 offsets (r13/r14-proven map):
//  [0, 32768)      W2h: W2 bf16 [256 rows][128 u32, XOR-swizzled]; yb aliases after A-frag build
//  [32768, 35328)  Vs fp32 [10][256] chain history
//  [35328, 37888)  W3s [10][256]
//  [37888, 38144)  Vbf [2][128] u32 bf16-pair ping-pong
//  [38144, 38272)  Ks [10][12] (+pad)
//  [38272, ...)    xs conv window (swizzled)
#define OFF_W2H 0
#define OFF_VS  32768
#define OFF_W3  35328
#define OFF_VBF 37888
#define OFF_KS  38144
#define OFF_XS  38272
#define XS_LOG  (TILE + DDEP)
#define SMEM_FLOATS (OFF_XS + XS_LOG + (XS_LOG >> 5) + 4)   // 161592 B < 160 KiB

__global__ __launch_bounds__(NTHR, 1) void fused_rnn_kernel(
    const float* __restrict__ x, const float* __restrict__ w1g,
    const float* __restrict__ W2, const float* __restrict__ W3,
    float* __restrict__ y)
{
    __shared__ float smem[SMEM_FLOATS];
    float* yb  = smem;                               // aliases W2h (epilogue only)
    unsigned* W2u = (unsigned*)(smem + OFF_W2H);
    float* Vs  = smem + OFF_VS;
    float* W3s = smem + OFF_W3;
    unsigned* Vbf = (unsigned*)(smem + OFF_VBF);
    float* Ks  = smem + OFF_KS;
    float* xs  = smem + OFF_XS;

    const int tid = threadIdx.x;
    const int bid = blockIdx.x;
    const int b   = bid >> 2;
    const int t0  = (bid & 3) * TILE;
    const float* xb = x + b * TLEN;

    // ---- stage W2 -> bf16 LDS (coalesced float4 reads; 16 iters/thread) ----
    const float4* W2v4 = (const float4*)W2;
    for (int g = tid; g < 16384; g += NTHR) {
        const float4 f = W2v4[g];
        const int row  = g >> 6;
        const int c    = (g & 63) * 2;               // u32 col (even)
        const int phys = c ^ ((row & 7) << 2);       // XOR-swizzle bits 2..4
        *(uint2*)&W2u[row * 128 + phys] =
            make_uint2(bfpk(f.x, f.y), bfpk(f.z, f.w));
    }

    // ---- stage xs (swizzled), W3s, v0 (fp32 + bf16) ----
    for (int j = tid; j < XS_LOG; j += NTHR) {
        const int g = t0 - DDEP + j;
        xs[ph(j)] = (g >= 0) ? xb[g] : 0.0f;
    }
    for (int i = tid; i < OUTD * Hd; i += NTHR) W3s[i] = W3[i];
    if (tid < Hd) Vs[tid] = w1g[tid];
    if (tid < 128) Vbf[tid] = bfpk(w1g[2 * tid], w1g[2 * tid + 1]);
    __syncthreads();

    // ---- build A-frags from LDS: chain waves 0-7, wave w owns rows [32w, 32w+32) ----
    const int w = tid >> 6, l = tid & 63;
    bf16x8 Afr[2][8];
    if (w < 8) {
        #pragma unroll
        for (int rt = 0; rt < 2; ++rt) {
            const int row = 32 * w + 16 * rt + (l & 15);
            #pragma unroll
            for (int kt = 0; kt < 8; ++kt) {
                const int c    = kt * 16 + (l >> 4) * 4;   // u32 col, 4-aligned
                const int phys = c ^ ((row & 7) << 2);
                Afr[rt][kt] = __builtin_bit_cast(bf16x8,
                    *(const int4*)&W2u[row * 128 + phys]);
            }
        }
    }
    __syncthreads();       // W2h dead from here; yb may overwrite later

    // ---- chain: v_{d+1} = W2 * v_d, 9 serial MFMA iterations (8 waves, r13 layout) ----
    #pragma unroll 1
    for (int d = 0; d < DDEP - 1; ++d) {
        if (w < 8) {
            const unsigned* vbf = Vbf + (d & 1) * 128;
            f32x4 acc0 = {0.f, 0.f, 0.f, 0.f};
            f32x4 acc1 = {0.f, 0.f, 0.f, 0.f};
            #pragma unroll
            for (int kt = 0; kt < 8; ++kt) {
                const bf16x8 Bfr = __builtin_bit_cast(bf16x8,
                    *(const int4*)&vbf[kt * 16 + (l >> 4) * 4]);
                acc0 = __builtin_amdgcn_mfma_f32_16x16x32_bf16(Afr[0][kt], Bfr, acc0, 0, 0, 0);
                acc1 = __builtin_amdgcn_mfma_f32_16x16x32_bf16(Afr[1][kt], Bfr, acc1, 0, 0, 0);
            }
            // C layout: col = lane&15, row = (lane>>4)*4 + reg (m89-verified)
            if ((l & 15) == 0) {
                const int g  = l >> 4;
                const int r0 = 32 * w + 4 * g;
                const int r1 = r0 + 16;
                *(f32x4*)&Vs[(d + 1) * Hd + r0] = acc0;
                *(f32x4*)&Vs[(d + 1) * Hd + r1] = acc1;
                unsigned* dst = Vbf + ((d + 1) & 1) * 128;
                *(uint2*)&dst[r0 >> 1] =
                    make_uint2(bfpk(acc0.x, acc0.y), bfpk(acc0.z, acc0.w));
                *(uint2*)&dst[r1 >> 1] =
                    make_uint2(bfpk(acc1.x, acc1.y), bfpk(acc1.z, acc1.w));
            }
        }
        __syncthreads();
    }

    // ---- K[d][o] = W3[o] . v_d : wave w handles d = w (w < 10) ----
    if (w < DDEP) {
        const int d = w;
        const float4 vv = ((const float4*)(Vs + d * Hd))[l];
        #pragma unroll
        for (int o = 0; o < OUTD; ++o) {
            const float4 wv = ((const float4*)(W3s + o * Hd))[l];
            float p = fmaf(wv.x, vv.x,
                      fmaf(wv.y, vv.y,
                      fmaf(wv.z, vv.z, wv.w * vv.w)));
            p += __shfl_xor(p, 1);  p += __shfl_xor(p, 2);
            p += __shfl_xor(p, 4);  p += __shfl_xor(p, 8);
            p += __shfl_xor(p, 16); p += __shfl_xor(p, 32);
            if (l == 0) Ks[d * KSTR + o] = p;
        }
        if (l == 1) { Ks[d * KSTR + 10] = 0.f; Ks[d * KSTR + 11] = 0.f; }
    }
    __syncthreads();

    // ---- causal FIR: 2 consecutive positions per thread ----
    const int ub = tid * 2;
    float acc0[OUTD], acc1[OUTD];
    #pragma unroll
    for (int o = 0; o < OUTD; ++o) { acc0[o] = 0.f; acc1[o] = 0.f; }

    float wn0 = xs[ph(ub + DDEP)];
    float wn1 = xs[ph(ub + DDEP + 1)];

    #pragma unroll
    for (int d = 0; d < DDEP; ++d) {
        const float4 kA = *(const float4*)&Ks[d * KSTR];
        const float4 kB = *(const float4*)&Ks[d * KSTR + 4];
        const float2 kC = *(const float2*)&Ks[d * KSTR + 8];
        acc0[0] = fmaf(kA.x, wn0, acc0[0]);  acc1[0] = fmaf(kA.x, wn1, acc1[0]);
        acc0[1] = fmaf(kA.y, wn0, acc0[1]);  acc1[1] = fmaf(kA.y, wn1, acc1[1]);
        acc0[2] = fmaf(kA.z, wn0, acc0[2]);  acc1[2] = fmaf(kA.z, wn1, acc1[2]);
        acc0[3] = fmaf(kA.w, wn0, acc0[3]);  acc1[3] = fmaf(kA.w, wn1, acc1[3]);
        acc0[4] = fmaf(kB.x, wn0, acc0[4]);  acc1[4] = fmaf(kB.x, wn1, acc1[4]);
        acc0[5] = fmaf(kB.y, wn0, acc0[5]);  acc1[5] = fmaf(kB.y, wn1, acc1[5]);
        acc0[6] = fmaf(kB.z, wn0, acc0[6]);  acc1[6] = fmaf(kB.z, wn1, acc1[6]);
        acc0[7] = fmaf(kB.w, wn0, acc0[7]);  acc1[7] = fmaf(kB.w, wn1, acc1[7]);
        acc0[8] = fmaf(kC.x, wn0, acc0[8]);  acc1[8] = fmaf(kC.x, wn1, acc1[8]);
        acc0[9] = fmaf(kC.y, wn0, acc0[9]);  acc1[9] = fmaf(kC.y, wn1, acc1[9]);
        wn1 = wn0;
        wn0 = xs[ph(ub + DDEP - 1 - d)];
    }

    // ---- transpose via LDS (stride 11), then coalesced nontemporal stores ----
    #pragma unroll
    for (int o = 0; o < OUTD; ++o) {
        yb[ub * 11 + o]      = acc0[o];
        yb[ub * 11 + 11 + o] = acc1[o];
    }
    __syncthreads();

    float* yg = y + ((size_t)b * TLEN + t0) * OUTD;
    #pragma unroll
    for (int pass = 0; pass < 5; ++pass) {
        const int l2 = (pass * NTHR + tid) * 4;
        f32x4 v;
        v.x = yb[l2     + (l2    ) / 10];
        v.y = yb[l2 + 1 + (l2 + 1) / 10];
        v.z = yb[l2 + 2 + (l2 + 2) / 10];
        v.w = yb[l2 + 3 + (l2 + 3) / 10];
        __builtin_nontemporal_store(v, (f32x4*)(yg + l2));
    }
}

extern "C" void kernel_launch(void* const* d_in, const int* in_sizes, int n_in,
                              void* d_out, int out_size, void* d_ws, size_t ws_size,
                              hipStream_t stream)
{
    const float* x  = (const float*)d_in[0];   // (64, 8192)
    const float* w1 = (const float*)d_in[1];   // (256, 1) contiguous
    const float* W2 = (const float*)d_in[2];   // (256, 256)
    const float* W3 = (const float*)d_in[3];   // (10, 256)
    float* y  = (float*)d_out;

    fused_rnn_kernel<<<NBLK, dim3(NTHR), 0, stream>>>(x, w1, W2, W3, y);
}